// Round 8
// baseline (401.694 us; speedup 1.0000x reference)
//
#include <hip/hip_runtime.h>
#include <math.h>

#define NPTS 2000000
#define GG 32
#define BLK 256

typedef float v4f __attribute__((ext_vector_type(4)));

// r7 post-mortem: ~40M line-requests at ~268 G req/s (16/cy/XCD-L2) + ~20us
// fixed models r3/r6/r7 well -> we are ~88% of the TCC request-service
// ceiling. Requests never merge across instructions, only across lanes
// within one instruction. r8: cooperative feat gather -- 16 lanes serve one
// point (8 rows x 2 dwordx4 slots at +0/+4 covering each 20B row), so one
// instruction carries 4 points whose addresses collapse to ~5.3 lines/pt:
// feat requests 12.5 -> ~5.3/pt (25M -> ~10.7M). Fragments go through LDS
// (frag stride 41, ofs stride 9: conflict-free), owners read back and run
// the EXACT original corner loop -> bit-identical results. btab = r7.
__global__ __launch_bounds__(256) void hashgrid_kernel(
    const float* __restrict__ x,
    const float* __restrict__ feat,
    const int* __restrict__ btab,
    float* __restrict__ out)
{
    // LDS map (floats):
    //   [0,10496)     frag[P=0..255][41]: row c at frag[P*41 + c*5 + f]
    //                 (reused: x-stage [0,768) before; out staging [0,5120) after)
    //   [10496,12800) ofs[P*9 + c] ints (stride 9 -> conflict-free)
    __shared__ float smem[12800];
    int* ofsl = (int*)&smem[10496];
    const int tid  = threadIdx.x;
    const int bid  = blockIdx.x;
    const int base = bid * BLK;
    const int cnt  = min(BLK, NPTS - base);   // 256, or 128 for the last block

    // ---- stage x (coalesced float4) ----
    {
        const float4* xin = (const float4*)(x + (size_t)base * 3);
        float4* s4 = (float4*)smem;
        int nf4 = (cnt * 3) >> 2;             // 192 or 96
        for (int i = tid; i < nf4; i += BLK) s4[i] = xin[i];
    }
    __syncthreads();

    float x0 = 0.f, x1 = 0.f, x2 = 0.f;
    if (tid < cnt) { x0 = smem[tid*3+0]; x1 = smem[tid*3+1]; x2 = smem[tid*3+2]; }

    // ---- btab phase (r7 structure: 1 RT, ~1.6 req/pt) ----
    float fr0 = 0.f, fr1 = 0.f, fr2 = 0.f;
    bool ok = false;
    int offs[8] = {0,0,0,0,0,0,0,0};
    if (tid < cnt) {
        // reference semantics: u = fl32(x * 100.0f), floor/frac in f32
        float u0 = x0 * 100.0f, u1 = x1 * 100.0f, u2 = x2 * 100.0f;
        float fl0 = floorf(u0), fl1 = floorf(u1), fl2 = floorf(u2);
        int xi0 = (int)fl0, xi1 = (int)fl1, xi2 = (int)fl2;
        fr0 = u0 - fl0; fr1 = u1 - fl1; fr2 = u2 - fl2;

        int vidx[8];
        #pragma unroll
        for (int c = 0; c < 8; ++c) {
            int i = (c >> 2) & 1, j = (c >> 1) & 1, k = c & 1;
            vidx[c] = (((xi0 + i) & 7) * 8 + ((xi1 + j) & 7)) * 8 + ((xi2 + k) & 7);
        }

        const bool fx = (xi0 & 7) == 7;
        const bool fy = (xi1 & 7) == 7;
        const bool cz = (xi2 & 7) == 7;
        const int ncross = (int)fx + (int)fy + (int)cz;
        const int blo = ((xi0 >> 3) * GG + (xi1 >> 3)) * GG + (xi2 >> 3);

        int bv0, bv1, bvm[8];
        int dsel = 0; bool hi_ok = true; bool inb[8];
        if (ncross == 0) {
            asm volatile("global_load_dword %0, %1, off"
                         : "=&v"(bv0) : "v"(btab + blo));
        } else if (ncross == 1) {
            dsel       = fx ? 4 : (fy ? 2 : 1);
            int stride = fx ? GG * GG : (fy ? GG : 1);
            int bcoord = fx ? (xi0 >> 3) : (fy ? (xi1 >> 3) : (xi2 >> 3));
            hi_ok      = (bcoord + 1) < GG;
            asm volatile("global_load_dword %0, %1, off"
                         : "=&v"(bv0) : "v"(btab + blo));
            asm volatile("global_load_dword %0, %1, off"
                         : "=&v"(bv1) : "v"(btab + blo + (hi_ok ? stride : 0)));
        } else {
            #pragma unroll
            for (int c = 0; c < 8; ++c) {
                int i = (c >> 2) & 1, j = (c >> 1) & 1, k = c & 1;
                int g0 = xi0 + i, g1 = xi1 + j, g2 = xi2 + k;
                int b0 = g0 >> 3, b1 = g1 >> 3, b2 = g2 >> 3;
                inb[c] = ((unsigned)b0 < GG) & ((unsigned)b1 < GG) & ((unsigned)b2 < GG);
                int c0 = min(max(b0,0),GG-1), c1 = min(max(b1,0),GG-1), c2 = min(max(b2,0),GG-1);
                asm volatile("global_load_dword %0, %1, off"
                             : "=&v"(bvm[c]) : "v"(btab + ((c0 * GG + c1) * GG + c2)));
            }
        }

        // first executed branch's wait drains all btab loads (vmcnt is wave-level)
        if (ncross == 0) {
            asm volatile("s_waitcnt vmcnt(0)" : "+v"(bv0));
            __builtin_amdgcn_sched_barrier(0);
            ok = bv0 >= 0;
            int bo = max(bv0, 0) * 520;
            #pragma unroll
            for (int c = 0; c < 8; ++c) offs[c] = bo + vidx[c];
        } else if (ncross == 1) {
            asm volatile("s_waitcnt vmcnt(0)" : "+v"(bv0), "+v"(bv1));
            __builtin_amdgcn_sched_barrier(0);
            ok = hi_ok & (bv0 >= 0) & (bv1 >= 0);
            int blo_s = max(bv0, 0) * 520;
            int bhi_s = max(bv1, 0) * 520;
            #pragma unroll
            for (int c = 0; c < 8; ++c)
                offs[c] = ((c & dsel) ? bhi_s : blo_s) + vidx[c];
        } else {
            asm volatile("s_waitcnt vmcnt(0)"
                         : "+v"(bvm[0]), "+v"(bvm[1]), "+v"(bvm[2]), "+v"(bvm[3]),
                           "+v"(bvm[4]), "+v"(bvm[5]), "+v"(bvm[6]), "+v"(bvm[7]));
            __builtin_amdgcn_sched_barrier(0);
            ok = true;
            #pragma unroll
            for (int c = 0; c < 8; ++c) {
                ok &= inb[c] & (bvm[c] >= 0);
                offs[c] = max(bvm[c], 0) * 520 + vidx[c];
            }
        }
        if (!ok) {
            #pragma unroll
            for (int c = 0; c < 8; ++c) offs[c] = 0;   // safe addr for servers
        }
    }

    // publish row offsets (all tids: tid>=cnt publishes zeros)
    #pragma unroll
    for (int c = 0; c < 8; ++c) ofsl[tid*9 + c] = offs[c];
    __syncthreads();

    // ---- cooperative feat gather: wave serves its own 64 points ----
    // lane = (sub<<4)|(c<<1)|s ; round r: point P = wbase + 4r + sub.
    // slot0: dwordx4 @ row+0  -> f0..f3 ; slot1: dwordx4 @ row+4B -> elem3 = f4.
    // Both slots + 8 rows of one point cluster into ~5.3 lines -> one
    // instruction (64 lanes, 4 points) ~21 requests vs 64 before.
    {
        const int lane  = tid & 63;
        const int wbase = tid & ~63;
        const int sub   = lane >> 4;
        const int cc    = (lane >> 1) & 7;
        const int ss    = lane & 1;
        int Pv[16]; int ov[16];
        #pragma unroll
        for (int r = 0; r < 16; ++r) {
            Pv[r] = wbase + r * 4 + sub;
            ov[r] = ofsl[Pv[r] * 9 + cc];
        }
        v4f q[16];
        #pragma unroll
        for (int r = 0; r < 16; ++r) {
            const float* fp = feat + (size_t)((unsigned)ov[r] * 5u + (unsigned)ss);
            asm volatile("global_load_dwordx4 %0, %1, off"
                         : "=&v"(q[r]) : "v"(fp));
        }
        asm volatile("s_waitcnt vmcnt(0)"
                     : "+v"(q[0]), "+v"(q[1]), "+v"(q[2]), "+v"(q[3]),
                       "+v"(q[4]), "+v"(q[5]), "+v"(q[6]), "+v"(q[7]),
                       "+v"(q[8]), "+v"(q[9]), "+v"(q[10]), "+v"(q[11]),
                       "+v"(q[12]), "+v"(q[13]), "+v"(q[14]), "+v"(q[15]));
        __builtin_amdgcn_sched_barrier(0);
        #pragma unroll
        for (int r = 0; r < 16; ++r) {
            float* fb = &smem[Pv[r] * 41 + cc * 5];
            if (ss == 0) {
                fb[0] = q[r][0]; fb[1] = q[r][1]; fb[2] = q[r][2]; fb[3] = q[r][3];
            } else {
                fb[4] = q[r][3];
            }
        }
    }
    __syncthreads();

    // ---- consume: owner reads back its 40 floats, ORIGINAL corner loop ----
    float accf[5] = {0,0,0,0,0};
    float adx[5]  = {0,0,0,0,0};
    float ady[5]  = {0,0,0,0,0};
    float adz[5]  = {0,0,0,0,0};
    float mval = 0.f;
    if (tid < cnt && ok) {
        mval = 1.f;
        float p0[2] = {1.f - fr0, fr0};
        float p1[2] = {1.f - fr1, fr1};
        float p2[2] = {1.f - fr2, fr2};
        const float* myf = &smem[tid * 41];
        #pragma unroll
        for (int c = 0; c < 8; ++c) {
            int i = (c >> 2) & 1, j = (c >> 1) & 1, k = c & 1;
            float wi = p0[i], wj = p1[j], wk = p2[k];
            float si = i ? 1.f : -1.f;
            float sj = j ? 1.f : -1.f;
            float sk = k ? 1.f : -1.f;
            float w   = wi * wj * wk;
            float dwx = si * wj * wk;
            float dwy = wi * sj * wk;
            float dwz = wi * wj * sk;
            #pragma unroll
            for (int f = 0; f < 5; ++f) {
                float v = myf[c * 5 + f];
                accf[f] += w   * v;
                adx[f]  += dwx * v;
                ady[f]  += dwy * v;
                adz[f]  += dwz * v;
            }
        }
    }
    __syncthreads();   // frag reads complete before staging overwrites

    // ---- stage outputs into LDS (odd strides 5/15 -> near-conflict-free) ----
    if (tid < cnt) {
        float* fs = smem + tid * 5;
        #pragma unroll
        for (int f = 0; f < 5; ++f) fs[f] = accf[f];
        float* ds = smem + 1280 + tid * 15;
        #pragma unroll
        for (int f = 0; f < 5; ++f) {
            ds[f*3+0] = adx[f] * 100.0f;
            ds[f*3+1] = ady[f] * 100.0f;
            ds[f*3+2] = adz[f] * 100.0f;
        }
        // mask: direct coalesced dword store
        out[(size_t)NPTS * 20 + base + tid] = mval;
    }
    __syncthreads();

    // ---- coalesced float4 global writes ----
    {
        const float4* s4 = (const float4*)smem;
        float4* o = (float4*)(out + (size_t)base * 5);
        int nf4 = (cnt * 5) >> 2;             // 320 or 160
        for (int i = tid; i < nf4; i += BLK) o[i] = s4[i];
    }
    {
        const float4* s4 = (const float4*)(smem + 1280);
        float4* o = (float4*)(out + (size_t)NPTS * 5 + (size_t)base * 15);
        int nf4 = (cnt * 15) >> 2;            // 960 or 480
        for (int i = tid; i < nf4; i += BLK) o[i] = s4[i];
    }
}

extern "C" void kernel_launch(void* const* d_in, const int* in_sizes, int n_in,
                              void* d_out, int out_size, void* d_ws, size_t ws_size,
                              hipStream_t stream) {
    const float* x    = (const float*)d_in[0];
    const float* feat = (const float*)d_in[1];
    const int*   btab = (const int*)d_in[2];
    float* out = (float*)d_out;
    int blocks = (NPTS + BLK - 1) / BLK;      // 7813
    hashgrid_kernel<<<blocks, BLK, 0, stream>>>(x, feat, btab, out);
}

// Round 10
// 398.827 us; speedup vs baseline: 1.0072x; 1.0072x over previous
//
#include <hip/hip_runtime.h>
#include <math.h>

#define NPTS 2000000
#define GG 32
#define BLK 256

typedef float v4f __attribute__((ext_vector_type(4)));

// r8 post-mortem: r7 (~40M line-req) and r8 (~26M) both 162-163us -> NOT
// request-bound. Pinned instead: FETCH/dur = 2.15 TB/s = 128 B/cy/XCD and
// total 3.2 TB/s. Cause of the 350MB FETCH: per-dispatch read set (feat 208
// + x 24 = 232 MB) fits L3 (256 MB), but 164 MB of output store-allocations
// thrash it -> feat re-fetched from HBM every dispatch. r9: non-temporal
// output stores (feats/dfeats/mask are write-once streaming) so they don't
// allocate in L2/L3; read set becomes L3-resident. Discriminator:
//   FETCH down + dur down  -> HBM random-BW wall (expected ~110-135us)
//   FETCH down + dur flat  -> L2 fill-port wall (pivot required)
//   FETCH flat             -> nt not honored (revert)
// r9 compile fix: nt-store through clang ext_vector v4f (HIP float4 is a
// class type the builtin rejects). Compute structure identical to r8.
__global__ __launch_bounds__(256) void hashgrid_kernel(
    const float* __restrict__ x,
    const float* __restrict__ feat,
    const int* __restrict__ btab,
    float* __restrict__ out)
{
    // LDS map (floats):
    //   [0,10496)     frag[P=0..255][41]: row c at frag[P*41 + c*5 + f]
    //                 (reused: x-stage [0,768) before; out staging [0,5120) after)
    //   [10496,12800) ofs[P*9 + c] ints (stride 9 -> conflict-free)
    __shared__ float smem[12800];
    int* ofsl = (int*)&smem[10496];
    const int tid  = threadIdx.x;
    const int bid  = blockIdx.x;
    const int base = bid * BLK;
    const int cnt  = min(BLK, NPTS - base);   // 256, or 128 for the last block

    // ---- stage x (coalesced float4) ----
    {
        const float4* xin = (const float4*)(x + (size_t)base * 3);
        float4* s4 = (float4*)smem;
        int nf4 = (cnt * 3) >> 2;             // 192 or 96
        for (int i = tid; i < nf4; i += BLK) s4[i] = xin[i];
    }
    __syncthreads();

    float x0 = 0.f, x1 = 0.f, x2 = 0.f;
    if (tid < cnt) { x0 = smem[tid*3+0]; x1 = smem[tid*3+1]; x2 = smem[tid*3+2]; }

    // ---- btab phase (r7 structure: 1 RT, ~1.6 req/pt) ----
    float fr0 = 0.f, fr1 = 0.f, fr2 = 0.f;
    bool ok = false;
    int offs[8] = {0,0,0,0,0,0,0,0};
    if (tid < cnt) {
        // reference semantics: u = fl32(x * 100.0f), floor/frac in f32
        float u0 = x0 * 100.0f, u1 = x1 * 100.0f, u2 = x2 * 100.0f;
        float fl0 = floorf(u0), fl1 = floorf(u1), fl2 = floorf(u2);
        int xi0 = (int)fl0, xi1 = (int)fl1, xi2 = (int)fl2;
        fr0 = u0 - fl0; fr1 = u1 - fl1; fr2 = u2 - fl2;

        int vidx[8];
        #pragma unroll
        for (int c = 0; c < 8; ++c) {
            int i = (c >> 2) & 1, j = (c >> 1) & 1, k = c & 1;
            vidx[c] = (((xi0 + i) & 7) * 8 + ((xi1 + j) & 7)) * 8 + ((xi2 + k) & 7);
        }

        const bool fx = (xi0 & 7) == 7;
        const bool fy = (xi1 & 7) == 7;
        const bool cz = (xi2 & 7) == 7;
        const int ncross = (int)fx + (int)fy + (int)cz;
        const int blo = ((xi0 >> 3) * GG + (xi1 >> 3)) * GG + (xi2 >> 3);

        int bv0, bv1, bvm[8];
        int dsel = 0; bool hi_ok = true; bool inb[8];
        if (ncross == 0) {
            asm volatile("global_load_dword %0, %1, off"
                         : "=&v"(bv0) : "v"(btab + blo));
        } else if (ncross == 1) {
            dsel       = fx ? 4 : (fy ? 2 : 1);
            int stride = fx ? GG * GG : (fy ? GG : 1);
            int bcoord = fx ? (xi0 >> 3) : (fy ? (xi1 >> 3) : (xi2 >> 3));
            hi_ok      = (bcoord + 1) < GG;
            asm volatile("global_load_dword %0, %1, off"
                         : "=&v"(bv0) : "v"(btab + blo));
            asm volatile("global_load_dword %0, %1, off"
                         : "=&v"(bv1) : "v"(btab + blo + (hi_ok ? stride : 0)));
        } else {
            #pragma unroll
            for (int c = 0; c < 8; ++c) {
                int i = (c >> 2) & 1, j = (c >> 1) & 1, k = c & 1;
                int g0 = xi0 + i, g1 = xi1 + j, g2 = xi2 + k;
                int b0 = g0 >> 3, b1 = g1 >> 3, b2 = g2 >> 3;
                inb[c] = ((unsigned)b0 < GG) & ((unsigned)b1 < GG) & ((unsigned)b2 < GG);
                int c0 = min(max(b0,0),GG-1), c1 = min(max(b1,0),GG-1), c2 = min(max(b2,0),GG-1);
                asm volatile("global_load_dword %0, %1, off"
                             : "=&v"(bvm[c]) : "v"(btab + ((c0 * GG + c1) * GG + c2)));
            }
        }

        // first executed branch's wait drains all btab loads (vmcnt is wave-level)
        if (ncross == 0) {
            asm volatile("s_waitcnt vmcnt(0)" : "+v"(bv0));
            __builtin_amdgcn_sched_barrier(0);
            ok = bv0 >= 0;
            int bo = max(bv0, 0) * 520;
            #pragma unroll
            for (int c = 0; c < 8; ++c) offs[c] = bo + vidx[c];
        } else if (ncross == 1) {
            asm volatile("s_waitcnt vmcnt(0)" : "+v"(bv0), "+v"(bv1));
            __builtin_amdgcn_sched_barrier(0);
            ok = hi_ok & (bv0 >= 0) & (bv1 >= 0);
            int blo_s = max(bv0, 0) * 520;
            int bhi_s = max(bv1, 0) * 520;
            #pragma unroll
            for (int c = 0; c < 8; ++c)
                offs[c] = ((c & dsel) ? bhi_s : blo_s) + vidx[c];
        } else {
            asm volatile("s_waitcnt vmcnt(0)"
                         : "+v"(bvm[0]), "+v"(bvm[1]), "+v"(bvm[2]), "+v"(bvm[3]),
                           "+v"(bvm[4]), "+v"(bvm[5]), "+v"(bvm[6]), "+v"(bvm[7]));
            __builtin_amdgcn_sched_barrier(0);
            ok = true;
            #pragma unroll
            for (int c = 0; c < 8; ++c) {
                ok &= inb[c] & (bvm[c] >= 0);
                offs[c] = max(bvm[c], 0) * 520 + vidx[c];
            }
        }
        if (!ok) {
            #pragma unroll
            for (int c = 0; c < 8; ++c) offs[c] = 0;   // safe addr for servers
        }
    }

    // publish row offsets (all tids: tid>=cnt publishes zeros)
    #pragma unroll
    for (int c = 0; c < 8; ++c) ofsl[tid*9 + c] = offs[c];
    __syncthreads();

    // ---- cooperative feat gather: wave serves its own 64 points ----
    // lane = (sub<<4)|(c<<1)|s ; round r: point P = wbase + 4r + sub.
    // slot0: dwordx4 @ row+0 -> f0..f3 ; slot1: dwordx4 @ row+4B -> elem3 = f4.
    {
        const int lane  = tid & 63;
        const int wbase = tid & ~63;
        const int sub   = lane >> 4;
        const int cc    = (lane >> 1) & 7;
        const int ss    = lane & 1;
        int Pv[16]; int ov[16];
        #pragma unroll
        for (int r = 0; r < 16; ++r) {
            Pv[r] = wbase + r * 4 + sub;
            ov[r] = ofsl[Pv[r] * 9 + cc];
        }
        v4f q[16];
        #pragma unroll
        for (int r = 0; r < 16; ++r) {
            const float* fp = feat + (size_t)((unsigned)ov[r] * 5u + (unsigned)ss);
            asm volatile("global_load_dwordx4 %0, %1, off"
                         : "=&v"(q[r]) : "v"(fp));
        }
        asm volatile("s_waitcnt vmcnt(0)"
                     : "+v"(q[0]), "+v"(q[1]), "+v"(q[2]), "+v"(q[3]),
                       "+v"(q[4]), "+v"(q[5]), "+v"(q[6]), "+v"(q[7]),
                       "+v"(q[8]), "+v"(q[9]), "+v"(q[10]), "+v"(q[11]),
                       "+v"(q[12]), "+v"(q[13]), "+v"(q[14]), "+v"(q[15]));
        __builtin_amdgcn_sched_barrier(0);
        #pragma unroll
        for (int r = 0; r < 16; ++r) {
            float* fb = &smem[Pv[r] * 41 + cc * 5];
            if (ss == 0) {
                fb[0] = q[r][0]; fb[1] = q[r][1]; fb[2] = q[r][2]; fb[3] = q[r][3];
            } else {
                fb[4] = q[r][3];
            }
        }
    }
    __syncthreads();

    // ---- consume: owner reads back its 40 floats, ORIGINAL corner loop ----
    float accf[5] = {0,0,0,0,0};
    float adx[5]  = {0,0,0,0,0};
    float ady[5]  = {0,0,0,0,0};
    float adz[5]  = {0,0,0,0,0};
    float mval = 0.f;
    if (tid < cnt && ok) {
        mval = 1.f;
        float p0[2] = {1.f - fr0, fr0};
        float p1[2] = {1.f - fr1, fr1};
        float p2[2] = {1.f - fr2, fr2};
        const float* myf = &smem[tid * 41];
        #pragma unroll
        for (int c = 0; c < 8; ++c) {
            int i = (c >> 2) & 1, j = (c >> 1) & 1, k = c & 1;
            float wi = p0[i], wj = p1[j], wk = p2[k];
            float si = i ? 1.f : -1.f;
            float sj = j ? 1.f : -1.f;
            float sk = k ? 1.f : -1.f;
            float w   = wi * wj * wk;
            float dwx = si * wj * wk;
            float dwy = wi * sj * wk;
            float dwz = wi * wj * sk;
            #pragma unroll
            for (int f = 0; f < 5; ++f) {
                float v = myf[c * 5 + f];
                accf[f] += w   * v;
                adx[f]  += dwx * v;
                ady[f]  += dwy * v;
                adz[f]  += dwz * v;
            }
        }
    }
    __syncthreads();   // frag reads complete before staging overwrites

    // ---- stage outputs into LDS (odd strides 5/15 -> near-conflict-free) ----
    if (tid < cnt) {
        float* fs = smem + tid * 5;
        #pragma unroll
        for (int f = 0; f < 5; ++f) fs[f] = accf[f];
        float* ds = smem + 1280 + tid * 15;
        #pragma unroll
        for (int f = 0; f < 5; ++f) {
            ds[f*3+0] = adx[f] * 100.0f;
            ds[f*3+1] = ady[f] * 100.0f;
            ds[f*3+2] = adz[f] * 100.0f;
        }
        // mask: direct coalesced dword store, non-temporal
        __builtin_nontemporal_store(mval, &out[(size_t)NPTS * 20 + base + tid]);
    }
    __syncthreads();

    // ---- coalesced 16B global writes (non-temporal: no L2/L3 alloc) ----
    // nt builtin requires scalar/ext_vector types -> use v4f, not HIP float4.
    {
        const v4f* s4 = (const v4f*)smem;
        v4f* o = (v4f*)(out + (size_t)base * 5);
        int nf4 = (cnt * 5) >> 2;             // 320 or 160
        for (int i = tid; i < nf4; i += BLK)
            __builtin_nontemporal_store(s4[i], &o[i]);
    }
    {
        const v4f* s4 = (const v4f*)(smem + 1280);
        v4f* o = (v4f*)(out + (size_t)NPTS * 5 + (size_t)base * 15);
        int nf4 = (cnt * 15) >> 2;            // 960 or 480
        for (int i = tid; i < nf4; i += BLK)
            __builtin_nontemporal_store(s4[i], &o[i]);
    }
}

extern "C" void kernel_launch(void* const* d_in, const int* in_sizes, int n_in,
                              void* d_out, int out_size, void* d_ws, size_t ws_size,
                              hipStream_t stream) {
    const float* x    = (const float*)d_in[0];
    const float* feat = (const float*)d_in[1];
    const int*   btab = (const int*)d_in[2];
    float* out = (float*)d_out;
    int blocks = (NPTS + BLK - 1) / BLK;      // 7813
    hashgrid_kernel<<<blocks, BLK, 0, stream>>>(x, feat, btab, out);
}